// Round 9
// baseline (1120.107 us; speedup 1.0000x reference)
//
#include <hip/hip_runtime.h>
#include <hip/hip_bf16.h>

typedef __hip_bfloat16 bf16;
typedef __attribute__((ext_vector_type(8))) short short8;
typedef __attribute__((ext_vector_type(4))) float f32x4;

#define N_NODES 50000
#define N_EDGES 1600000
#define FIN 8
#define HD 64
#define NH (N_NODES * HD)
#define NLAYERS 3

// CSR build geometry
#define RSLC 256                 // row slices, E/RSLC = 6250
#define EPR (N_EDGES / RSLC)     // 6250 edges per row-slice
#define NWORDS 12500             // 50000 nodes as packed u8 in u32
#define DSLC 64                  // degree slices, E/DSLC = 25000
#define EPD (N_EDGES / DSLC)
#define DSUB 8192                // degree subrange size
#define NDSUB 7                  // ceil(50000/8192)
#define COLC (25000u << 16)      // col-half boundary (packed compare)

__device__ __forceinline__ float b2f(bf16 v) { return __bfloat162float(v); }
__device__ __forceinline__ float bu2f(unsigned int u) { return __uint_as_float(u << 16); }
__device__ __forceinline__ unsigned short f2bu(float f) {
    unsigned int x = __float_as_uint(f);
    unsigned int r = x + 0x7FFFu + ((x >> 16) & 1u);
    return (unsigned short)(r >> 16);
}

// ---------------- dtype detection ----------------
__global__ void k_detect(const void* __restrict__ ew, int* __restrict__ flag) {
    int ok = 1;
    for (int i = threadIdx.x; i < 512; i += 64) {
        float v = b2f(((const bf16*)ew)[i]);
        if (!(v >= 0.f && v <= 1.f)) ok = 0;
    }
    unsigned long long m = __ballot(ok);
    if (threadIdx.x == 0) *flag = (m == 0xFFFFFFFFFFFFFFFFull) ? 0 : 1;
}

struct ConvArgs {
    const void* src[14];
    float* dst[14];
    int cum[15];
};

__global__ void k_conv_small(ConvArgs a, const int* __restrict__ flag) {
    int q = blockIdx.x * 256 + threadIdx.x;
    if (q >= a.cum[14]) return;
    int s = 0;
    while (q >= a.cum[s + 1]) ++s;
    int off = q - a.cum[s];
    if (*flag) a.dst[s][off] = ((const float*)a.src[s])[off];
    else       a.dst[s][off] = bu2f(((const unsigned short*)a.src[s])[off]);
}

// ---------------- CSR build: byte-packed LDS histograms, no global atomics ----------------

__global__ void __launch_bounds__(256) k_hist_row(const int* __restrict__ ei,
                                                  unsigned int* __restrict__ pcnt_u32) {
    __shared__ unsigned int sm[NWORDS];
    int b = blockIdx.x, t = threadIdx.x;
    for (int i = t; i < NWORDS; i += 256) sm[i] = 0;
    __syncthreads();
    int ebase = b * EPR;
    for (int el = t; el < EPR; el += 256) {
        int r = ei[ebase + el];
        atomicAdd(&sm[r >> 2], 1u << ((r & 3) * 8));
    }
    __syncthreads();
    unsigned int* dst = pcnt_u32 + (size_t)b * NWORDS;
    for (int i = t; i < NWORDS; i += 256) dst[i] = sm[i];
}

__global__ void __launch_bounds__(256) k_hist_deg(const int* __restrict__ ei,
                                                  const void* __restrict__ ewr,
                                                  const int* __restrict__ flag,
                                                  float* __restrict__ pdeg) {
    __shared__ float sm[DSUB];
    int b = blockIdx.x, t = threadIdx.x;
    int slice = b / NDSUB, sub = b % NDSUB;
    for (int i = t; i < DSUB; i += 256) sm[i] = 0.f;
    __syncthreads();
    int f32 = *flag;
    int ebase = slice * EPD;
    for (int el = t; el < EPD; el += 256) {
        int e = ebase + el;
        int c = ei[N_EDGES + e];
        if ((c >> 13) == sub) {
            float w = f32 ? ((const float*)ewr)[e] : bu2f(((const unsigned short*)ewr)[e]);
            atomicAdd(&sm[c & (DSUB - 1)], w);
        }
    }
    __syncthreads();
    int nbase = sub << 13;
    float* dst = pdeg + (size_t)slice * N_NODES;
    for (int i = t; i < DSUB; i += 256) {
        int n = nbase + i;
        if (n < N_NODES) dst[n] = sm[i];
    }
}

// per-node: 256-slice u8 prefix -> pref16, total -> cnt, degree sum -> dis,
// plus per-block count sum -> bsum (feeds hierarchical scan)
__global__ void k_merge(const unsigned char* __restrict__ pcnt8,
                        const float* __restrict__ pdeg,
                        int* __restrict__ cnt, float* __restrict__ dis,
                        unsigned short* __restrict__ pref16, int* __restrict__ bsum) {
    __shared__ int red[256];
    int t = threadIdx.x;
    int n = blockIdx.x * 256 + t;
    int run = 0;
    if (n < N_NODES) {
#pragma unroll 8
        for (int s = 0; s < RSLC; ++s) {
            pref16[(size_t)s * N_NODES + n] = (unsigned short)run;
            run += pcnt8[(size_t)s * N_NODES + n];
        }
        cnt[n] = run;
        float d = 0.f;
#pragma unroll 8
        for (int s = 0; s < DSLC; ++s) d += pdeg[(size_t)s * N_NODES + n];
        dis[n] = fminf(rsqrtf(d), 1e6f);   // rsqrt(0)=inf -> 1e6, matches ref clamp
    }
    red[t] = run;
    __syncthreads();
    for (int off = 128; off; off >>= 1) {
        if (t < off) red[t] += red[t + off];
        __syncthreads();
    }
    if (t == 0) bsum[blockIdx.x] = red[0];
}

// hierarchical scan: 1-block scan of 196 block sums
__global__ void k_scan_top(const int* __restrict__ bsum, int* __restrict__ bpre,
                           int* __restrict__ row_ptr) {
    __shared__ int sm[256];
    int t = threadIdx.x;
    int v = (t < 196) ? bsum[t] : 0;
    sm[t] = v;
    __syncthreads();
    int val = v;
    for (int off = 1; off < 256; off <<= 1) {
        int other = (t >= off) ? sm[t - off] : 0;
        __syncthreads();
        val += other;
        sm[t] = val;
        __syncthreads();
    }
    bpre[t] = val - v;  // exclusive
    if (t == 0) row_ptr[N_NODES] = N_EDGES;
}

// 196 blocks: intra-block exclusive scan + block base -> row_ptr
__global__ void k_scan_fin(const int* __restrict__ cnt, const int* __restrict__ bpre,
                           int* __restrict__ row_ptr) {
    __shared__ int sm[256];
    int t = threadIdx.x;
    int n = blockIdx.x * 256 + t;
    int v = (n < N_NODES) ? cnt[n] : 0;
    sm[t] = v;
    __syncthreads();
    int val = v;
    for (int off = 1; off < 256; off <<= 1) {
        int other = (t >= off) ? sm[t - off] : 0;
        __syncthreads();
        val += other;
        sm[t] = val;
        __syncthreads();
    }
    if (n < N_NODES) row_ptr[n] = bpre[blockIdx.x] + val - v;
}

// placement A: per-slice u8 ordinal in LDS; scatter only perm[pos] = e (4 B payload)
__global__ void __launch_bounds__(256) k_placeA(const int* __restrict__ ei,
                                                const int* __restrict__ row_ptr,
                                                const unsigned short* __restrict__ pref16,
                                                int* __restrict__ perm) {
    __shared__ unsigned int sm[NWORDS];
    int b = blockIdx.x, t = threadIdx.x;
    for (int i = t; i < NWORDS; i += 256) sm[i] = 0;
    __syncthreads();
    int ebase = b * EPR;
    const unsigned short* pr = pref16 + (size_t)b * N_NODES;
    for (int el = t; el < EPR; el += 256) {
        int e = ebase + el;
        int r = ei[e];
        int sh = (r & 3) * 8;
        unsigned old = atomicAdd(&sm[r >> 2], 1u << sh);
        int ord = (old >> sh) & 0xFF;
        int pos = row_ptr[r] + pr[r] + ord;
        perm[pos] = e;
    }
}

// placement B: coalesced expansion of perm into pairs4/pairs8
__global__ void k_placeB(const int* __restrict__ ei, const void* __restrict__ ewr,
                         const float* __restrict__ dis, const int* __restrict__ perm,
                         const int* __restrict__ flag,
                         unsigned int* __restrict__ pairs4, int2* __restrict__ pairs8) {
    int pos = blockIdx.x * 256 + threadIdx.x;
    if (pos >= N_EDGES) return;
    int e = perm[pos];
    int r = ei[e], c = ei[N_EDGES + e];
    float w = (*flag) ? ((const float*)ewr)[e] : bu2f(((const unsigned short*)ewr)[e]);
    float nrm = dis[r] * w * dis[c];
    pairs4[pos] = ((unsigned)c << 16) | (unsigned)f2bu(nrm);
    int2 p8;
    p8.x = c | (r << 16);
    p8.y = e;
    pairs8[pos] = p8;
}

// in-row bitonic sort of pairs4 by col + split = #cols<25000 (order-independent count).
// Correctness of the two-range spmm needs only multiset preservation, not sortedness.
__global__ void __launch_bounds__(256) k_sort_split(const int* __restrict__ row_ptr,
                                                    unsigned int* __restrict__ pairs4,
                                                    int* __restrict__ split) {
    int wv = (blockIdx.x * 256 + threadIdx.x) >> 6;
    int lane = threadIdx.x & 63;
    if (wv >= N_NODES) return;
    int s = row_ptr[wv], e = row_ptr[wv + 1];
    int len = e - s;
    if (len > 128) {           // rare/never at E/N=32: leave unsorted, single range
        if (lane == 0) split[wv] = s;
        return;
    }
    unsigned v0 = (s + lane < e) ? pairs4[s + lane] : 0xFFFFFFFFu;
    unsigned v1 = (s + 64 + lane < e) ? pairs4[s + 64 + lane] : 0xFFFFFFFFu;
    if (len > 1) {
#pragma unroll
        for (int k = 2; k <= 128; k <<= 1) {
#pragma unroll
            for (int j = k >> 1; j >= 1; j >>= 1) {
                if (j == 64) {
                    unsigned lo = min(v0, v1), hi = max(v0, v1);
                    v0 = lo; v1 = hi;
                } else {
                    unsigned o0 = (unsigned)__shfl_xor((int)v0, j, 64);
                    unsigned o1 = (unsigned)__shfl_xor((int)v1, j, 64);
                    bool lower = ((lane & j) == 0);
                    bool up0 = ((lane & k) == 0) || (k == 128);
                    bool up1 = (((lane | 64) & k) == 0) || (k == 128);
                    v0 = (lower == up0) ? min(v0, o0) : max(v0, o0);
                    v1 = (lower == up1) ? min(v1, o1) : max(v1, o1);
                }
            }
        }
        if (s + lane < e) pairs4[s + lane] = v0;
        if (s + 64 + lane < e) pairs4[s + 64 + lane] = v1;
    }
    unsigned long long m0 = __ballot(v0 < COLC);
    unsigned long long m1 = __ballot(v1 < COLC);
    if (lane == 0) split[wv] = s + __popcll(m0) + __popcll(m1);
}

// ---------------- input projection ----------------

__global__ void k_inproj(const void* __restrict__ xr_, const float* __restrict__ W,
                         const float* __restrict__ b, float* __restrict__ h,
                         unsigned short* __restrict__ h_bf, const int* __restrict__ flag) {
    __shared__ float Wt[FIN * HD];
    __shared__ float bs[HD];
    int t = threadIdx.x;
    int f32 = *flag;
    for (int idx = t; idx < FIN * HD; idx += 256) {
        int f = idx >> 3, j = idx & 7;
        Wt[j * 64 + f] = W[idx];
    }
    if (t < 64) bs[t] = b[t];
    __syncthreads();
    int gid = blockIdx.x * 256 + t;
    if (gid < NH) {
        int i = gid >> 6, f = gid & 63;
        const float* xf = (const float*)xr_ + i * FIN;
        const unsigned short* xb = (const unsigned short*)xr_ + i * FIN;
        float acc = bs[f];
#pragma unroll
        for (int j = 0; j < FIN; ++j) {
            float xv = f32 ? xf[j] : bu2f(xb[j]);
            acc += xv * Wt[j * 64 + f];
        }
        h[gid] = acc;
        h_bf[gid] = f2bu(acc);
    }
}

// ---------------- stats + coefficient MLP ----------------

__global__ void k_stats(const float* __restrict__ h, float* __restrict__ stats) {
    __shared__ float ssum[256], ssq[256];
    int t = threadIdx.x;
    float ls = 0.f, lq = 0.f;
    for (int idx = blockIdx.x * 256 + t; idx < NH; idx += 102400) {
        float v = h[idx];
        ls += v; lq += v * v;
    }
    ssum[t] = ls; ssq[t] = lq;
    __syncthreads();
    if (t < 64) {
        float a = ssum[t] + ssum[t + 64] + ssum[t + 128] + ssum[t + 192];
        atomicAdd(&stats[t], a);
        float q = ssq[t] + ssq[t + 64] + ssq[t + 128] + ssq[t + 192];
        for (int off = 32; off; off >>= 1) q += __shfl_down(q, off, 64);
        if (t == 0) atomicAdd(&stats[64], q);
    }
}

__global__ void k_coeffs(const float* __restrict__ stats,
                         const float* __restrict__ W1, const float* __restrict__ b1,
                         const float* __restrict__ W2, const float* __restrict__ b2,
                         int layer, float* __restrict__ coeffs) {
    __shared__ float ci[68];
    __shared__ float hid[32];
    __shared__ float lg[6];
    int t = threadIdx.x;
    float sf = stats[t];
    float tot = sf;
    for (int off = 1; off < 64; off <<= 1) tot += __shfl_xor(tot, off, 64);
    ci[t] = sf / (float)N_NODES;
    if (t == 0) {
        float sumsq = stats[64];
        float mean = tot / (float)NH;
        float var = (sumsq - (float)NH * mean * mean) / (float)(NH - 1);
        ci[64] = mean;
        ci[65] = sqrtf(fmaxf(var, 0.f));
        ci[66] = (float)N_NODES;
        ci[67] = (float)N_EDGES;
    }
    __syncthreads();
    if (t < 32) {
        float a = b1[layer * 32 + t];
        const float* wr = W1 + (layer * 32 + t) * 68;
        for (int j = 0; j < 68; ++j) a += ci[j] * wr[j];
        hid[t] = fmaxf(a, 0.f);
    }
    __syncthreads();
    if (t < 6) {
        float a = b2[layer * 6 + t];
        const float* wr = W2 + (layer * 6 + t) * 32;
        for (int g = 0; g < 32; ++g) a += hid[g] * wr[g];
        lg[t] = a;
    }
    __syncthreads();
    if (t == 0) {
        float mx = lg[0];
        for (int p = 1; p < 6; ++p) mx = fmaxf(mx, lg[p]);
        float s = 0.f, e[6];
        for (int p = 0; p < 6; ++p) { e[p] = expf(lg[p] - mx); s += e[p]; }
        for (int p = 0; p < 6; ++p) coeffs[p] = e[p] / s;
    }
}

// ---------------- SpMM hop: wave per node, two col-half ranges for L2 locality --------

__device__ __forceinline__ float acc_range(const unsigned short* __restrict__ txo,
                                           const unsigned int* __restrict__ pairs4,
                                           int j0, int j1, int lane, float acc) {
    int j = j0;
    for (; j + 7 < j1; j += 8) {
        unsigned p0 = pairs4[j],     p1 = pairs4[j + 1], p2 = pairs4[j + 2], p3 = pairs4[j + 3];
        unsigned p4 = pairs4[j + 4], p5 = pairs4[j + 5], p6 = pairs4[j + 6], p7 = pairs4[j + 7];
        float g0 = bu2f(txo[(p0 >> 16) * 64 + lane]);
        float g1 = bu2f(txo[(p1 >> 16) * 64 + lane]);
        float g2 = bu2f(txo[(p2 >> 16) * 64 + lane]);
        float g3 = bu2f(txo[(p3 >> 16) * 64 + lane]);
        float g4 = bu2f(txo[(p4 >> 16) * 64 + lane]);
        float g5 = bu2f(txo[(p5 >> 16) * 64 + lane]);
        float g6 = bu2f(txo[(p6 >> 16) * 64 + lane]);
        float g7 = bu2f(txo[(p7 >> 16) * 64 + lane]);
        acc += bu2f(p0 & 0xFFFFu) * g0 + bu2f(p1 & 0xFFFFu) * g1 +
               bu2f(p2 & 0xFFFFu) * g2 + bu2f(p3 & 0xFFFFu) * g3;
        acc += bu2f(p4 & 0xFFFFu) * g4 + bu2f(p5 & 0xFFFFu) * g5 +
               bu2f(p6 & 0xFFFFu) * g6 + bu2f(p7 & 0xFFFFu) * g7;
    }
    for (; j < j1; ++j) {
        unsigned p = pairs4[j];
        acc += bu2f(p & 0xFFFFu) * bu2f(txo[(p >> 16) * 64 + lane]);
    }
    return acc;
}

__global__ void __launch_bounds__(256) k_spmm(
    const unsigned short* __restrict__ txo, unsigned short* __restrict__ txn,
    const int* __restrict__ row_ptr, const int* __restrict__ split,
    const unsigned int* __restrict__ pairs4) {
    int lane = threadIdx.x & 63;
    int wv = __builtin_amdgcn_readfirstlane((int)(blockIdx.x * 4 + (threadIdx.x >> 6)));
    int s = __builtin_amdgcn_readfirstlane(row_ptr[wv]);
    int m = __builtin_amdgcn_readfirstlane(split[wv]);
    int e = __builtin_amdgcn_readfirstlane(row_ptr[wv + 1]);
    float acc = acc_range(txo, pairs4, s, m, lane, 0.f);
    acc = acc_range(txo, pairs4, m, e, lane, acc);
    txn[wv * 64 + lane] = f2bu(acc);
}

// ---------------- fused last hop + polynomial combine + layernorm ----------------

__global__ void __launch_bounds__(256) k_spmm_ln(
    const unsigned short* __restrict__ txo,
    const int* __restrict__ row_ptr, const int* __restrict__ split,
    const unsigned int* __restrict__ pairs4,
    float* __restrict__ h, unsigned short* __restrict__ h_bf,
    const unsigned short* __restrict__ t1, const unsigned short* __restrict__ t2,
    const unsigned short* __restrict__ t3, const unsigned short* __restrict__ t4,
    const float* __restrict__ coeffs,
    const float* __restrict__ sc, const float* __restrict__ bi,
    int layer, int last, void* __restrict__ outv, const int* __restrict__ flag) {
    int lane = threadIdx.x & 63;
    int wv = __builtin_amdgcn_readfirstlane((int)(blockIdx.x * 4 + (threadIdx.x >> 6)));
    int s = __builtin_amdgcn_readfirstlane(row_ptr[wv]);
    int mm = __builtin_amdgcn_readfirstlane(split[wv]);
    int e = __builtin_amdgcn_readfirstlane(row_ptr[wv + 1]);
    float acc = acc_range(txo, pairs4, s, mm, lane, 0.f);
    acc = acc_range(txo, pairs4, mm, e, lane, acc);
    int o = wv * 64 + lane;
    float c0 = coeffs[0], c1 = coeffs[1], c2 = coeffs[2],
          c3 = coeffs[3], c4 = coeffs[4], c5 = coeffs[5];
    float v = (1.f + c0) * h[o] + c1 * bu2f(t1[o]) + c2 * bu2f(t2[o]) +
              c3 * bu2f(t3[o]) + c4 * bu2f(t4[o]) + c5 * acc;
    float m = v;
    for (int off = 1; off < 64; off <<= 1) m += __shfl_xor(m, off, 64);
    m *= (1.f / 64.f);
    float d = v - m;
    float q = d * d;
    for (int off = 1; off < 64; off <<= 1) q += __shfl_xor(q, off, 64);
    float var = q * (1.f / 64.f);
    float y = d / sqrtf(var + 1e-5f) * sc[layer * 64 + lane] + bi[layer * 64 + lane];
    h[o] = y;
    h_bf[o] = f2bu(y);
    if (last) {
        if (*flag) ((float*)outv)[N_EDGES + o] = y;
        else       ((unsigned short*)outv)[N_EDGES + o] = f2bu(y);
    }
}

// ---------------- edge predictor ----------------

__global__ void __launch_bounds__(256) k_uv(const float* __restrict__ h,
                                            const float* __restrict__ W1,
                                            unsigned short* __restrict__ ub,
                                            unsigned short* __restrict__ vb) {
    __shared__ float Wt[128 * 65];
    __shared__ float hs[4 * 64];
    int t = threadIdx.x;
    for (int idx = t; idx < 8192; idx += 256) {
        int f = idx >> 7, j = idx & 127;
        Wt[j * 65 + f] = W1[idx];
    }
    int node0 = blockIdx.x * 4;
    hs[t] = h[node0 * 64 + t];
    __syncthreads();
    int ni = t >> 6, f = t & 63;
    const float* hr = hs + ni * 64;
    float au = 0.f, av = 0.f;
#pragma unroll 8
    for (int j = 0; j < 64; ++j) {
        float xv = hr[j];
        au += Wt[j * 65 + f] * xv;
        av += Wt[(j + 64) * 65 + f] * xv;
    }
    int i = node0 + ni;
    ub[i * 64 + f] = f2bu(au);
    vb[i * 64 + f] = f2bu(av);
}

// MFMA edge predictor: 16 CSR-ordered edges per wave-iteration.
__global__ void __launch_bounds__(256) k_edgepred(
    const unsigned short* __restrict__ ub, const unsigned short* __restrict__ vb,
    const int2* __restrict__ pairs8,
    const float* __restrict__ eb1, const float* __restrict__ eW2,
    const float* __restrict__ eb2, const float* __restrict__ eW3,
    const float* __restrict__ eb3,
    void* __restrict__ outv, const int* __restrict__ flag) {
    int t = threadIdx.x;
    int lane = t & 63;
    int m = lane & 15, q = lane >> 4;
    int f32o = *flag;

    short8 B00, B01, B10, B11;
#pragma unroll
    for (int j = 0; j < 8; ++j) {
        B00[j] = (short)f2bu(eW2[(m) * 64      + q * 8 + j]);
        B01[j] = (short)f2bu(eW2[(m) * 64 + 32 + q * 8 + j]);
        B10[j] = (short)f2bu(eW2[(m + 16) * 64      + q * 8 + j]);
        B11[j] = (short)f2bu(eW2[(m + 16) * 64 + 32 + q * 8 + j]);
    }
    float b1f0[8], b1f1[8];
#pragma unroll
    for (int j = 0; j < 8; ++j) {
        b1f0[j] = eb1[q * 8 + j];
        b1f1[j] = eb1[32 + q * 8 + j];
    }
    float w3a = eW3[m], w3b = eW3[16 + m];
    float b2a = eb2[m], b2b = eb2[16 + m];
    float b3v = eb3[0];

    int gw = blockIdx.x * 4 + (t >> 6);
    const int NW = 1563 * 4;
    for (int tile = gw; tile < N_EDGES / 16; tile += NW) {
        int base = tile << 4;
        int2 pm = pairs8[base + m];
        int col = pm.x & 0xFFFF;
        int row = ((unsigned)pm.x) >> 16;
        int eidv = pm.y;
        const unsigned short* up = ub + row * 64;
        const unsigned short* vp = vb + col * 64;
        uint4 U0 = *(const uint4*)(up + q * 8);
        uint4 U1 = *(const uint4*)(up + 32 + q * 8);
        uint4 V0 = *(const uint4*)(vp + q * 8);
        uint4 V1 = *(const uint4*)(vp + 32 + q * 8);
        short8 A0, A1;
        {
            unsigned uu[4] = {U0.x, U0.y, U0.z, U0.w};
            unsigned vv[4] = {V0.x, V0.y, V0.z, V0.w};
#pragma unroll
            for (int w = 0; w < 4; ++w) {
                float e0 = fmaxf(bu2f(uu[w] & 0xFFFFu) + bu2f(vv[w] & 0xFFFFu) + b1f0[2 * w], 0.f);
                float e1 = fmaxf(bu2f(uu[w] >> 16)     + bu2f(vv[w] >> 16)     + b1f0[2 * w + 1], 0.f);
                A0[2 * w] = (short)f2bu(e0);
                A0[2 * w + 1] = (short)f2bu(e1);
            }
        }
        {
            unsigned uu[4] = {U1.x, U1.y, U1.z, U1.w};
            unsigned vv[4] = {V1.x, V1.y, V1.z, V1.w};
#pragma unroll
            for (int w = 0; w < 4; ++w) {
                float e0 = fmaxf(bu2f(uu[w] & 0xFFFFu) + bu2f(vv[w] & 0xFFFFu) + b1f1[2 * w], 0.f);
                float e1 = fmaxf(bu2f(uu[w] >> 16)     + bu2f(vv[w] >> 16)     + b1f1[2 * w + 1], 0.f);
                A1[2 * w] = (short)f2bu(e0);
                A1[2 * w + 1] = (short)f2bu(e1);
            }
        }
        f32x4 acc0 = {0.f, 0.f, 0.f, 0.f};
        f32x4 acc1 = {0.f, 0.f, 0.f, 0.f};
        acc0 = __builtin_amdgcn_mfma_f32_16x16x32_bf16(A0, B00, acc0, 0, 0, 0);
        acc0 = __builtin_amdgcn_mfma_f32_16x16x32_bf16(A1, B01, acc0, 0, 0, 0);
        acc1 = __builtin_amdgcn_mfma_f32_16x16x32_bf16(A0, B10, acc1, 0, 0, 0);
        acc1 = __builtin_amdgcn_mfma_f32_16x16x32_bf16(A1, B11, acc1, 0, 0, 0);
        float z[4];
#pragma unroll
        for (int rr = 0; rr < 4; ++rr) {
            z[rr] = w3a * fmaxf(acc0[rr] + b2a, 0.f) + w3b * fmaxf(acc1[rr] + b2b, 0.f);
            z[rr] += __shfl_xor(z[rr], 1, 64);
            z[rr] += __shfl_xor(z[rr], 2, 64);
            z[rr] += __shfl_xor(z[rr], 4, 64);
            z[rr] += __shfl_xor(z[rr], 8, 64);
        }
#pragma unroll
        for (int rr = 0; rr < 4; ++rr) {
            int src = (q << 4) + (q << 2) + rr;
            int eidr = __shfl(eidv, src, 64);
            if (m == 0) {
                float p = 1.f / (1.f + __expf(-(z[rr] + b3v)));
                if (f32o) ((float*)outv)[eidr] = p;
                else      ((unsigned short*)outv)[eidr] = f2bu(p);
            }
        }
    }
}

// ---------------- launch ----------------

extern "C" void kernel_launch(void* const* d_in, const int* in_sizes, int n_in,
                              void* d_out, int out_size, void* d_ws, size_t ws_size,
                              hipStream_t stream) {
    (void)in_sizes; (void)n_in; (void)out_size; (void)ws_size;
    const void* x_r   = d_in[0];
    const int*  ei    = (const int*)d_in[1];
    const void* ew_r  = d_in[2];

    char* w = (char*)d_ws;
    float* h            = (float*)w;          w += (size_t)NH * 4;       // 12.8 MB
    unsigned short* hbf = (unsigned short*)w; w += (size_t)NH * 2;       // 6.4
    char* txr           = w;                  w += (size_t)NH * 8;       // 25.6 (4 bufs)
    unsigned int* pairs4 = (unsigned int*)w;  w += (size_t)N_EDGES * 4;  // 6.4
    int2* pairs8        = (int2*)w;           w += (size_t)N_EDGES * 8;  // 12.8
    int* row_ptr        = (int*)w;            w += 200192;
    int* cnt            = (int*)w;            w += 200192;
    float* dis          = (float*)w;          w += 200192;
    int* split          = (int*)w;            w += 200192;
    float* cWin = (float*)w; w += 2048;
    float* cbin = (float*)w; w += 256;
    float* ccW1 = (float*)w; w += 26112;
    float* ccb1 = (float*)w; w += 384;
    float* ccW2 = (float*)w; w += 2304;
    float* ccb2 = (float*)w; w += 128;
    float* clns = (float*)w; w += 768;
    float* clnb = (float*)w; w += 768;
    float* ceW1 = (float*)w; w += 32768;
    float* ceb1 = (float*)w; w += 256;
    float* ceW2 = (float*)w; w += 8192;
    float* ceb2 = (float*)w; w += 128;
    float* ceW3 = (float*)w; w += 128;
    float* ceb3 = (float*)w; w += 128;
    int* bsum = (int*)w; w += 1024;
    int* bpre = (int*)w; w += 1024;
    char* zero_base = w;
    float* stats = (float*)w; w += 1024;
    size_t zero_bytes = (size_t)(w - zero_base);
    float* coeffs = (float*)w; w += 128;
    int*   flag   = (int*)w;   w += 128;

    // setup-phase overlays (lifetimes disjoint with hosts):
    //  pcnt8  (12.8 MB, 256 x 50000 u8)  -> pairs8 region [hist_row -> merge]
    //  pdeg   (12.8 MB, 64 x 50000 f32)  -> h region      [hist_deg -> merge]
    //  pref16 (25.6 MB, 256 x 50000 u16) -> txr           [merge -> placeA]
    //  perm   (6.4 MB)                   -> hbf region    [placeA -> placeB]
    unsigned int* pcnt_u32 = (unsigned int*)pairs8;
    unsigned char* pcnt8   = (unsigned char*)pairs8;
    float* pdeg            = (float*)h;
    unsigned short* pref16 = (unsigned short*)txr;
    int* perm              = (int*)hbf;

    unsigned short* tx[4];
    for (int k = 0; k < 4; ++k) tx[k] = (unsigned short*)txr + (size_t)k * NH;
    unsigned short* ub = tx[0];   // k_uv runs after last spmm_ln: tx dead
    unsigned short* vb = tx[1];

    hipMemsetAsync(zero_base, 0, zero_bytes, stream);

    k_detect<<<1, 64, 0, stream>>>(ew_r, flag);

    ConvArgs ca;
    const void* srcs[14] = {d_in[3], d_in[4], d_in[5], d_in[6], d_in[7], d_in[8], d_in[9],
                            d_in[10], d_in[11], d_in[12], d_in[13], d_in[14], d_in[15], d_in[16]};
    float* dsts[14] = {cWin, cbin, ccW1, ccb1, ccW2, ccb2, clns,
                       clnb, ceW1, ceb1, ceW2, ceb2, ceW3, ceb3};
    int sizes[14] = {512, 64, 6528, 96, 576, 18, 192, 192, 8192, 64, 2048, 32, 32, 1};
    int c = 0;
    for (int i = 0; i < 14; ++i) { ca.src[i] = srcs[i]; ca.dst[i] = dsts[i]; ca.cum[i] = c; c += sizes[i]; }
    ca.cum[14] = c;
    k_conv_small<<<(c + 255) / 256, 256, 0, stream>>>(ca, flag);

    k_hist_row<<<RSLC, 256, 0, stream>>>(ei, pcnt_u32);
    k_hist_deg<<<DSLC * NDSUB, 256, 0, stream>>>(ei, ew_r, flag, pdeg);
    k_merge<<<196, 256, 0, stream>>>(pcnt8, pdeg, cnt, dis, pref16, bsum);
    k_scan_top<<<1, 256, 0, stream>>>(bsum, bpre, row_ptr);
    k_scan_fin<<<196, 256, 0, stream>>>(cnt, bpre, row_ptr);
    k_placeA<<<RSLC, 256, 0, stream>>>(ei, row_ptr, pref16, perm);
    k_placeB<<<6250, 256, 0, stream>>>(ei, ew_r, dis, perm, flag, pairs4, pairs8);
    k_sort_split<<<12500, 256, 0, stream>>>(row_ptr, pairs4, split);
    k_inproj<<<12500, 256, 0, stream>>>(x_r, cWin, cbin, h, hbf, flag);

    for (int l = 0; l < NLAYERS; ++l) {
        k_stats<<<400, 256, 0, stream>>>(h, stats + l * 80);
        k_coeffs<<<1, 64, 0, stream>>>(stats + l * 80, ccW1, ccb1, ccW2, ccb2, l,
                                       coeffs + l * 8);
        const unsigned short* src = hbf;
        for (int k = 0; k < 4; ++k) {
            k_spmm<<<12500, 256, 0, stream>>>(src, tx[k], row_ptr, split, pairs4);
            src = tx[k];
        }
        k_spmm_ln<<<12500, 256, 0, stream>>>(tx[3], row_ptr, split, pairs4, h, hbf,
                                             tx[0], tx[1], tx[2], tx[3],
                                             coeffs + l * 8, clns, clnb, l,
                                             (l == NLAYERS - 1) ? 1 : 0, d_out, flag);
    }

    k_uv<<<12500, 256, 0, stream>>>(h, ceW1, ub, vb);
    k_edgepred<<<1563, 256, 0, stream>>>(ub, vb, pairs8, ceb1, ceW2, ceb2, ceW3, ceb3,
                                         d_out, flag);
}

// Round 11
// 926.987 us; speedup vs baseline: 1.2083x; 1.2083x over previous
//
#include <hip/hip_runtime.h>
#include <hip/hip_bf16.h>
#include <hip/hip_fp16.h>

typedef __hip_bfloat16 bf16;
typedef __attribute__((ext_vector_type(8))) short short8;
typedef __attribute__((ext_vector_type(8))) _Float16 half8;
typedef __attribute__((ext_vector_type(2))) _Float16 half2v;
typedef __attribute__((ext_vector_type(4))) float f32x4;

#define N_NODES 50000
#define N_EDGES 1600000
#define FIN 8
#define HD 64
#define NH (N_NODES * HD)
#define NLAYERS 3

// CSR build geometry
#define RSLC 256                 // row slices, E/RSLC = 6250
#define EPR (N_EDGES / RSLC)
#define NWORDS 12500             // 50000 nodes as packed u8 in u32
#define DSLC 64                  // degree slices, E/DSLC = 25000
#define EPD (N_EDGES / DSLC)
#define DSUB 8192
#define NDSUB 7

__device__ __forceinline__ float b2f(bf16 v) { return __bfloat162float(v); }
__device__ __forceinline__ float bu2f(unsigned int u) { return __uint_as_float(u << 16); }
__device__ __forceinline__ unsigned short f2bu(float f) {
    unsigned int x = __float_as_uint(f);
    unsigned int r = x + 0x7FFFu + ((x >> 16) & 1u);
    return (unsigned short)(r >> 16);
}
__device__ __forceinline__ unsigned short f2h(float f) {
    _Float16 h = (_Float16)f;
    return *(unsigned short*)&h;
}

// ---------------- dtype detection ----------------
__global__ void k_detect(const void* __restrict__ ew, int* __restrict__ flag) {
    int ok = 1;
    for (int i = threadIdx.x; i < 512; i += 64) {
        float v = b2f(((const bf16*)ew)[i]);
        if (!(v >= 0.f && v <= 1.f)) ok = 0;
    }
    unsigned long long m = __ballot(ok);
    if (threadIdx.x == 0) *flag = (m == 0xFFFFFFFFFFFFFFFFull) ? 0 : 1;
}

struct ConvArgs {
    const void* src[14];
    float* dst[14];
    int cum[15];
};

__global__ void k_conv_small(ConvArgs a, const int* __restrict__ flag) {
    int q = blockIdx.x * 256 + threadIdx.x;
    if (q >= a.cum[14]) return;
    int s = 0;
    while (q >= a.cum[s + 1]) ++s;
    int off = q - a.cum[s];
    if (*flag) a.dst[s][off] = ((const float*)a.src[s])[off];
    else       a.dst[s][off] = bu2f(((const unsigned short*)a.src[s])[off]);
}

// ---------------- CSR build: byte-packed LDS histograms, no global atomics ----------------

__global__ void __launch_bounds__(256) k_hist_row(const int* __restrict__ ei,
                                                  unsigned int* __restrict__ pcnt_u32) {
    __shared__ unsigned int sm[NWORDS];
    int b = blockIdx.x, t = threadIdx.x;
    for (int i = t; i < NWORDS; i += 256) sm[i] = 0;
    __syncthreads();
    int ebase = b * EPR;
    for (int el = t; el < EPR; el += 256) {
        int r = ei[ebase + el];
        atomicAdd(&sm[r >> 2], 1u << ((r & 3) * 8));
    }
    __syncthreads();
    unsigned int* dst = pcnt_u32 + (size_t)b * NWORDS;
    for (int i = t; i < NWORDS; i += 256) dst[i] = sm[i];
}

// XCD-swizzled: slice = b % DSLC so all NDSUB sub-blocks of a slice share b%8 -> same XCD L2
__global__ void __launch_bounds__(256) k_hist_deg(const int* __restrict__ ei,
                                                  const void* __restrict__ ewr,
                                                  const int* __restrict__ flag,
                                                  float* __restrict__ pdeg) {
    __shared__ float sm[DSUB];
    int b = blockIdx.x, t = threadIdx.x;
    int slice = b % DSLC, sub = b / DSLC;
    for (int i = t; i < DSUB; i += 256) sm[i] = 0.f;
    __syncthreads();
    int f32 = *flag;
    int ebase = slice * EPD;
    for (int el = t; el < EPD; el += 256) {
        int e = ebase + el;
        int c = ei[N_EDGES + e];
        if ((c >> 13) == sub) {
            float w = f32 ? ((const float*)ewr)[e] : bu2f(((const unsigned short*)ewr)[e]);
            atomicAdd(&sm[c & (DSUB - 1)], w);
        }
    }
    __syncthreads();
    int nbase = sub << 13;
    float* dst = pdeg + (size_t)slice * N_NODES;
    for (int i = t; i < DSUB; i += 256) {
        int n = nbase + i;
        if (n < N_NODES) dst[n] = sm[i];
    }
}

// per-node: 256-slice u8 prefix -> pref16, total -> cnt, degree sum -> dis, block sums
__global__ void k_merge(const unsigned char* __restrict__ pcnt8,
                        const float* __restrict__ pdeg,
                        int* __restrict__ cnt, float* __restrict__ dis,
                        unsigned short* __restrict__ pref16, int* __restrict__ bsum) {
    __shared__ int red[256];
    int t = threadIdx.x;
    int n = blockIdx.x * 256 + t;
    int run = 0;
    if (n < N_NODES) {
#pragma unroll 8
        for (int s = 0; s < RSLC; ++s) {
            pref16[(size_t)s * N_NODES + n] = (unsigned short)run;
            run += pcnt8[(size_t)s * N_NODES + n];
        }
        cnt[n] = run;
        float d = 0.f;
#pragma unroll 8
        for (int s = 0; s < DSLC; ++s) d += pdeg[(size_t)s * N_NODES + n];
        dis[n] = fminf(rsqrtf(d), 1e6f);   // rsqrt(0)=inf -> 1e6, matches ref clamp
    }
    red[t] = run;
    __syncthreads();
    for (int off = 128; off; off >>= 1) {
        if (t < off) red[t] += red[t + off];
        __syncthreads();
    }
    if (t == 0) bsum[blockIdx.x] = red[0];
}

__global__ void k_scan_top(const int* __restrict__ bsum, int* __restrict__ bpre,
                           int* __restrict__ row_ptr) {
    __shared__ int sm[256];
    int t = threadIdx.x;
    int v = (t < 196) ? bsum[t] : 0;
    sm[t] = v;
    __syncthreads();
    int val = v;
    for (int off = 1; off < 256; off <<= 1) {
        int other = (t >= off) ? sm[t - off] : 0;
        __syncthreads();
        val += other;
        sm[t] = val;
        __syncthreads();
    }
    bpre[t] = val - v;
    if (t == 0) row_ptr[N_NODES] = N_EDGES;
}

__global__ void k_scan_fin(const int* __restrict__ cnt, const int* __restrict__ bpre,
                           int* __restrict__ row_ptr) {
    __shared__ int sm[256];
    int t = threadIdx.x;
    int n = blockIdx.x * 256 + t;
    int v = (n < N_NODES) ? cnt[n] : 0;
    sm[t] = v;
    __syncthreads();
    int val = v;
    for (int off = 1; off < 256; off <<= 1) {
        int other = (t >= off) ? sm[t - off] : 0;
        __syncthreads();
        val += other;
        sm[t] = val;
        __syncthreads();
    }
    if (n < N_NODES) row_ptr[n] = bpre[blockIdx.x] + val - v;
}

// placement A: per-slice u8 ordinal in LDS; scatter perm[pos]=e (4B), coalesced iperm[e]=pos
__global__ void __launch_bounds__(256) k_placeA(const int* __restrict__ ei,
                                                const int* __restrict__ row_ptr,
                                                const unsigned short* __restrict__ pref16,
                                                int* __restrict__ perm,
                                                int* __restrict__ iperm) {
    __shared__ unsigned int sm[NWORDS];
    int b = blockIdx.x, t = threadIdx.x;
    for (int i = t; i < NWORDS; i += 256) sm[i] = 0;
    __syncthreads();
    int ebase = b * EPR;
    const unsigned short* pr = pref16 + (size_t)b * N_NODES;
    for (int el = t; el < EPR; el += 256) {
        int e = ebase + el;
        int r = ei[e];
        int sh = (r & 3) * 8;
        unsigned old = atomicAdd(&sm[r >> 2], 1u << sh);
        int ord = (old >> sh) & 0xFF;
        int pos = row_ptr[r] + pr[r] + ord;
        perm[pos] = e;       // scattered 4 B
        iperm[e] = pos;      // coalesced
    }
}

// placement B: coalesced expansion of perm into pairs4 / rc
__global__ void k_placeB(const int* __restrict__ ei, const void* __restrict__ ewr,
                         const float* __restrict__ dis, const int* __restrict__ perm,
                         const int* __restrict__ flag,
                         unsigned int* __restrict__ pairs4, unsigned int* __restrict__ rc) {
    int pos = blockIdx.x * 256 + threadIdx.x;
    if (pos >= N_EDGES) return;
    int e = perm[pos];
    int r = ei[e], c = ei[N_EDGES + e];
    float w = (*flag) ? ((const float*)ewr)[e] : bu2f(((const unsigned short*)ewr)[e]);
    float nrm = dis[r] * w * dis[c];
    pairs4[pos] = ((unsigned)c << 16) | (unsigned)f2bu(nrm);
    rc[pos] = (unsigned)c | ((unsigned)r << 16);
}

// ---------------- input projection ----------------

__global__ void k_inproj(const void* __restrict__ xr_, const float* __restrict__ W,
                         const float* __restrict__ b, float* __restrict__ h,
                         unsigned short* __restrict__ h_bf, const int* __restrict__ flag) {
    __shared__ float Wt[FIN * HD];
    __shared__ float bs[HD];
    int t = threadIdx.x;
    int f32 = *flag;
    for (int idx = t; idx < FIN * HD; idx += 256) {
        int f = idx >> 3, j = idx & 7;
        Wt[j * 64 + f] = W[idx];
    }
    if (t < 64) bs[t] = b[t];
    __syncthreads();
    int gid = blockIdx.x * 256 + t;
    if (gid < NH) {
        int i = gid >> 6, f = gid & 63;
        const float* xf = (const float*)xr_ + i * FIN;
        const unsigned short* xb = (const unsigned short*)xr_ + i * FIN;
        float acc = bs[f];
#pragma unroll
        for (int j = 0; j < FIN; ++j) {
            float xv = f32 ? xf[j] : bu2f(xb[j]);
            acc += xv * Wt[j * 64 + f];
        }
        h[gid] = acc;
        h_bf[gid] = f2bu(acc);
    }
}

// ---------------- stats + coefficient MLP ----------------

__global__ void k_stats(const float* __restrict__ h, float* __restrict__ stats) {
    __shared__ float ssum[256], ssq[256];
    int t = threadIdx.x;
    float ls = 0.f, lq = 0.f;
    for (int idx = blockIdx.x * 256 + t; idx < NH; idx += 102400) {
        float v = h[idx];
        ls += v; lq += v * v;
    }
    ssum[t] = ls; ssq[t] = lq;
    __syncthreads();
    if (t < 64) {
        float a = ssum[t] + ssum[t + 64] + ssum[t + 128] + ssum[t + 192];
        atomicAdd(&stats[t], a);
        float q = ssq[t] + ssq[t + 64] + ssq[t + 128] + ssq[t + 192];
        for (int off = 32; off; off >>= 1) q += __shfl_down(q, off, 64);
        if (t == 0) atomicAdd(&stats[64], q);
    }
}

__global__ void k_coeffs(const float* __restrict__ stats,
                         const float* __restrict__ W1, const float* __restrict__ b1,
                         const float* __restrict__ W2, const float* __restrict__ b2,
                         int layer, float* __restrict__ coeffs) {
    __shared__ float ci[68];
    __shared__ float hid[32];
    __shared__ float lg[6];
    int t = threadIdx.x;
    float sf = stats[t];
    float tot = sf;
    for (int off = 1; off < 64; off <<= 1) tot += __shfl_xor(tot, off, 64);
    ci[t] = sf / (float)N_NODES;
    if (t == 0) {
        float sumsq = stats[64];
        float mean = tot / (float)NH;
        float var = (sumsq - (float)NH * mean * mean) / (float)(NH - 1);
        ci[64] = mean;
        ci[65] = sqrtf(fmaxf(var, 0.f));
        ci[66] = (float)N_NODES;
        ci[67] = (float)N_EDGES;
    }
    __syncthreads();
    if (t < 32) {
        float a = b1[layer * 32 + t];
        const float* wr = W1 + (layer * 32 + t) * 68;
        for (int j = 0; j < 68; ++j) a += ci[j] * wr[j];
        hid[t] = fmaxf(a, 0.f);
    }
    __syncthreads();
    if (t < 6) {
        float a = b2[layer * 6 + t];
        const float* wr = W2 + (layer * 6 + t) * 32;
        for (int g = 0; g < 32; ++g) a += hid[g] * wr[g];
        lg[t] = a;
    }
    __syncthreads();
    if (t == 0) {
        float mx = lg[0];
        for (int p = 1; p < 6; ++p) mx = fmaxf(mx, lg[p]);
        float s = 0.f, e[6];
        for (int p = 0; p < 6; ++p) { e[p] = expf(lg[p] - mx); s += e[p]; }
        for (int p = 0; p < 6; ++p) coeffs[p] = e[p] / s;
    }
}

// ---------------- SpMM hop: wave per node, 16-deep gather unroll ----------------

__device__ __forceinline__ float acc_range(const unsigned short* __restrict__ txo,
                                           const unsigned int* __restrict__ pairs4,
                                           int j0, int j1, int lane, float acc) {
    int j = j0;
    for (; j + 15 < j1; j += 16) {
        unsigned p0 = pairs4[j],      p1 = pairs4[j + 1],  p2 = pairs4[j + 2],  p3 = pairs4[j + 3];
        unsigned p4 = pairs4[j + 4],  p5 = pairs4[j + 5],  p6 = pairs4[j + 6],  p7 = pairs4[j + 7];
        unsigned p8 = pairs4[j + 8],  p9 = pairs4[j + 9],  pa = pairs4[j + 10], pb = pairs4[j + 11];
        unsigned pc = pairs4[j + 12], pd = pairs4[j + 13], pe = pairs4[j + 14], pf = pairs4[j + 15];
        float g0 = bu2f(txo[(p0 >> 16) * 64 + lane]);
        float g1 = bu2f(txo[(p1 >> 16) * 64 + lane]);
        float g2 = bu2f(txo[(p2 >> 16) * 64 + lane]);
        float g3 = bu2f(txo[(p3 >> 16) * 64 + lane]);
        float g4 = bu2f(txo[(p4 >> 16) * 64 + lane]);
        float g5 = bu2f(txo[(p5 >> 16) * 64 + lane]);
        float g6 = bu2f(txo[(p6 >> 16) * 64 + lane]);
        float g7 = bu2f(txo[(p7 >> 16) * 64 + lane]);
        float g8 = bu2f(txo[(p8 >> 16) * 64 + lane]);
        float g9 = bu2f(txo[(p9 >> 16) * 64 + lane]);
        float ga = bu2f(txo[(pa >> 16) * 64 + lane]);
        float gb = bu2f(txo[(pb >> 16) * 64 + lane]);
        float gc = bu2f(txo[(pc >> 16) * 64 + lane]);
        float gd = bu2f(txo[(pd >> 16) * 64 + lane]);
        float ge = bu2f(txo[(pe >> 16) * 64 + lane]);
        float gf = bu2f(txo[(pf >> 16) * 64 + lane]);
        acc += bu2f(p0 & 0xFFFFu) * g0 + bu2f(p1 & 0xFFFFu) * g1 +
               bu2f(p2 & 0xFFFFu) * g2 + bu2f(p3 & 0xFFFFu) * g3;
        acc += bu2f(p4 & 0xFFFFu) * g4 + bu2f(p5 & 0xFFFFu) * g5 +
               bu2f(p6 & 0xFFFFu) * g6 + bu2f(p7 & 0xFFFFu) * g7;
        acc += bu2f(p8 & 0xFFFFu) * g8 + bu2f(p9 & 0xFFFFu) * g9 +
               bu2f(pa & 0xFFFFu) * ga + bu2f(pb & 0xFFFFu) * gb;
        acc += bu2f(pc & 0xFFFFu) * gc + bu2f(pd & 0xFFFFu) * gd +
               bu2f(pe & 0xFFFFu) * ge + bu2f(pf & 0xFFFFu) * gf;
    }
    for (; j + 7 < j1; j += 8) {
        unsigned p0 = pairs4[j],     p1 = pairs4[j + 1], p2 = pairs4[j + 2], p3 = pairs4[j + 3];
        unsigned p4 = pairs4[j + 4], p5 = pairs4[j + 5], p6 = pairs4[j + 6], p7 = pairs4[j + 7];
        float g0 = bu2f(txo[(p0 >> 16) * 64 + lane]);
        float g1 = bu2f(txo[(p1 >> 16) * 64 + lane]);
        float g2 = bu2f(txo[(p2 >> 16) * 64 + lane]);
        float g3 = bu2f(txo[(p3 >> 16) * 64 + lane]);
        float g4 = bu2f(txo[(p4 >> 16) * 64 + lane]);
        float g5 = bu2f(txo[(p5 >> 16) * 64 + lane]);
        float g6 = bu2f(txo[(p6 >> 16) * 64 + lane]);
        float g7 = bu2f(txo[(p7 >> 16) * 64 + lane]);
        acc += bu2f(p0 & 0xFFFFu) * g0 + bu2f(p1 & 0xFFFFu) * g1 +
               bu2f(p2 & 0xFFFFu) * g2 + bu2f(p3 & 0xFFFFu) * g3;
        acc += bu2f(p4 & 0xFFFFu) * g4 + bu2f(p5 & 0xFFFFu) * g5 +
               bu2f(p6 & 0xFFFFu) * g6 + bu2f(p7 & 0xFFFFu) * g7;
    }
    for (; j < j1; ++j) {
        unsigned p = pairs4[j];
        acc += bu2f(p & 0xFFFFu) * bu2f(txo[(p >> 16) * 64 + lane]);
    }
    return acc;
}

__global__ void __launch_bounds__(256) k_spmm(
    const unsigned short* __restrict__ txo, unsigned short* __restrict__ txn,
    const int* __restrict__ row_ptr, const unsigned int* __restrict__ pairs4) {
    int lane = threadIdx.x & 63;
    int wv = __builtin_amdgcn_readfirstlane((int)(blockIdx.x * 4 + (threadIdx.x >> 6)));
    int s = __builtin_amdgcn_readfirstlane(row_ptr[wv]);
    int e = __builtin_amdgcn_readfirstlane(row_ptr[wv + 1]);
    float acc = acc_range(txo, pairs4, s, e, lane, 0.f);
    txn[wv * 64 + lane] = f2bu(acc);
}

// ---------------- fused last hop + polynomial combine + layernorm ----------------

__global__ void __launch_bounds__(256) k_spmm_ln(
    const unsigned short* __restrict__ txo,
    const int* __restrict__ row_ptr, const unsigned int* __restrict__ pairs4,
    float* __restrict__ h, unsigned short* __restrict__ h_bf,
    const unsigned short* __restrict__ t1, const unsigned short* __restrict__ t2,
    const unsigned short* __restrict__ t3, const unsigned short* __restrict__ t4,
    const float* __restrict__ coeffs,
    const float* __restrict__ sc, const float* __restrict__ bi,
    int layer, int last, void* __restrict__ outv, const int* __restrict__ flag) {
    int lane = threadIdx.x & 63;
    int wv = __builtin_amdgcn_readfirstlane((int)(blockIdx.x * 4 + (threadIdx.x >> 6)));
    int s = __builtin_amdgcn_readfirstlane(row_ptr[wv]);
    int e = __builtin_amdgcn_readfirstlane(row_ptr[wv + 1]);
    float acc = acc_range(txo, pairs4, s, e, lane, 0.f);
    int o = wv * 64 + lane;
    float c0 = coeffs[0], c1 = coeffs[1], c2 = coeffs[2],
          c3 = coeffs[3], c4 = coeffs[4], c5 = coeffs[5];
    float v = (1.f + c0) * h[o] + c1 * bu2f(t1[o]) + c2 * bu2f(t2[o]) +
              c3 * bu2f(t3[o]) + c4 * bu2f(t4[o]) + c5 * acc;
    float m = v;
    for (int off = 1; off < 64; off <<= 1) m += __shfl_xor(m, off, 64);
    m *= (1.f / 64.f);
    float d = v - m;
    float q = d * d;
    for (int off = 1; off < 64; off <<= 1) q += __shfl_xor(q, off, 64);
    float var = q * (1.f / 64.f);
    float y = d / sqrtf(var + 1e-5f) * sc[layer * 64 + lane] + bi[layer * 64 + lane];
    h[o] = y;
    h_bf[o] = f2bu(y);
    if (last) {
        if (*flag) ((float*)outv)[N_EDGES + o] = y;
        else       ((unsigned short*)outv)[N_EDGES + o] = f2bu(y);
    }
}

// ---------------- edge predictor (fp16) ----------------

__global__ void __launch_bounds__(256) k_uv(const float* __restrict__ h,
                                            const float* __restrict__ W1,
                                            unsigned short* __restrict__ ub,
                                            unsigned short* __restrict__ vb) {
    __shared__ float Wt[128 * 65];
    __shared__ float hs[4 * 64];
    int t = threadIdx.x;
    for (int idx = t; idx < 8192; idx += 256) {
        int f = idx >> 7, j = idx & 127;
        Wt[j * 65 + f] = W1[idx];
    }
    int node0 = blockIdx.x * 4;
    hs[t] = h[node0 * 64 + t];
    __syncthreads();
    int ni = t >> 6, f = t & 63;
    const float* hr = hs + ni * 64;
    float au = 0.f, av = 0.f;
#pragma unroll 8
    for (int j = 0; j < 64; ++j) {
        float xv = hr[j];
        au += Wt[j * 65 + f] * xv;
        av += Wt[(j + 64) * 65 + f] * xv;
    }
    int i = node0 + ni;
    ub[i * 64 + f] = f2h(au);   // fp16 bits
    vb[i * 64 + f] = f2h(av);
}

// packed fp16 relu(u + v + b) via native _Float16 vectors (avoids __hmax2 overload clash)
__device__ __forceinline__ unsigned h2rel(unsigned uu, unsigned vv, half2v b) {
    half2v a = *(half2v*)&uu + *(half2v*)&vv + b;
    a[0] = a[0] > (_Float16)0 ? a[0] : (_Float16)0;
    a[1] = a[1] > (_Float16)0 ? a[1] : (_Float16)0;
    return *(unsigned*)&a;
}

union U4H8 { uint4 u; half8 h; };

// MFMA f16 edge predictor: 16 CSR-ordered edges per wave-iteration; coalesced tmp output
__global__ void __launch_bounds__(256) k_edgepred(
    const unsigned short* __restrict__ ub, const unsigned short* __restrict__ vb,
    const unsigned int* __restrict__ rc,
    const float* __restrict__ eb1, const float* __restrict__ eW2,
    const float* __restrict__ eb2, const float* __restrict__ eW3,
    const float* __restrict__ eb3, float* __restrict__ tmpP) {
    int t = threadIdx.x;
    int lane = t & 63;
    int m = lane & 15, q = lane >> 4;

    half8 B00, B01, B10, B11;
#pragma unroll
    for (int j = 0; j < 8; ++j) {
        B00[j] = (_Float16)eW2[(m) * 64      + q * 8 + j];
        B01[j] = (_Float16)eW2[(m) * 64 + 32 + q * 8 + j];
        B10[j] = (_Float16)eW2[(m + 16) * 64      + q * 8 + j];
        B11[j] = (_Float16)eW2[(m + 16) * 64 + 32 + q * 8 + j];
    }
    half2v b1p0[4], b1p1[4];
#pragma unroll
    for (int wq = 0; wq < 4; ++wq) {
        b1p0[wq][0] = (_Float16)eb1[q * 8 + 2 * wq];
        b1p0[wq][1] = (_Float16)eb1[q * 8 + 2 * wq + 1];
        b1p1[wq][0] = (_Float16)eb1[32 + q * 8 + 2 * wq];
        b1p1[wq][1] = (_Float16)eb1[32 + q * 8 + 2 * wq + 1];
    }
    float w3a = eW3[m], w3b = eW3[16 + m];
    float b2a = eb2[m], b2b = eb2[16 + m];
    float b3v = eb3[0];

    int gw = blockIdx.x * 4 + (t >> 6);
    const int NW = 1563 * 4;
    for (int tile = gw; tile < N_EDGES / 16; tile += NW) {
        int base = tile << 4;
        unsigned rcv = rc[base + m];
        int col = rcv & 0xFFFF;
        int row = rcv >> 16;
        const unsigned short* up = ub + row * 64;
        const unsigned short* vp = vb + col * 64;
        uint4 U0 = *(const uint4*)(up + q * 8);
        uint4 U1 = *(const uint4*)(up + 32 + q * 8);
        uint4 V0 = *(const uint4*)(vp + q * 8);
        uint4 V1 = *(const uint4*)(vp + 32 + q * 8);
        U4H8 a0, a1;
        a0.u.x = h2rel(U0.x, V0.x, b1p0[0]);
        a0.u.y = h2rel(U0.y, V0.y, b1p0[1]);
        a0.u.z = h2rel(U0.z, V0.z, b1p0[2]);
        a0.u.w = h2rel(U0.w, V0.w, b1p0[3]);
        a1.u.x = h2rel(U1.x, V1.x, b1p1[0]);
        a1.u.y = h2rel(U1.y, V1.y, b1p1[1]);
        a1.u.z = h2rel(U1.z, V1.z, b1p1[2]);
        a1.u.w = h2rel(U1.w, V1.w, b1p1[3]);
        f32x4 acc0 = {0.f, 0.f, 0.f, 0.f};
        f32x4 acc1 = {0.f, 0.f, 0.f, 0.f};
        acc0 = __builtin_amdgcn_mfma_f32_16x16x32_f16(a0.h, B00, acc0, 0, 0, 0);
        acc0 = __builtin_amdgcn_mfma_f32_16x16x32_f16(a1.h, B01, acc0, 0, 0, 0);
        acc1 = __builtin_amdgcn_mfma_f32_16x16x32_f16(a0.h, B10, acc1, 0, 0, 0);
        acc1 = __builtin_amdgcn_mfma_f32_16x16x32_f16(a1.h, B11, acc1, 0, 0, 0);
        float z[4];
#pragma unroll
        for (int rr = 0; rr < 4; ++rr) {
            z[rr] = w3a * fmaxf(acc0[rr] + b2a, 0.f) + w3b * fmaxf(acc1[rr] + b2b, 0.f);
            z[rr] += __shfl_xor(z[rr], 1, 64);
            z[rr] += __shfl_xor(z[rr], 2, 64);
            z[rr] += __shfl_xor(z[rr], 4, 64);
            z[rr] += __shfl_xor(z[rr], 8, 64);
        }
        if (m == 0) {
#pragma unroll
            for (int rr = 0; rr < 4; ++rr) {
                float p = 1.f / (1.f + __expf(-(z[rr] + b3v)));
                tmpP[base + (q << 2) + rr] = p;   // coalesced (16 B per lane)
            }
        }
    }
}

// final: out[e] = tmpP[iperm[e]] (coalesced read+write; tmpP gather is L2-resident)
__global__ void k_out(const int* __restrict__ iperm, const float* __restrict__ tmpP,
                      void* __restrict__ outv, const int* __restrict__ flag) {
    int e = blockIdx.x * 256 + threadIdx.x;
    if (e >= N_EDGES) return;
    float p = tmpP[iperm[e]];
    if (*flag) ((float*)outv)[e] = p;
    else       ((unsigned short*)outv)[e] = f2bu(p);
}

// ---------------- launch ----------------

extern "C" void kernel_launch(void* const* d_in, const int* in_sizes, int n_in,
                              void* d_out, int out_size, void* d_ws, size_t ws_size,
                              hipStream_t stream) {
    (void)in_sizes; (void)n_in; (void)out_size; (void)ws_size;
    const void* x_r   = d_in[0];
    const int*  ei    = (const int*)d_in[1];
    const void* ew_r  = d_in[2];

    char* w = (char*)d_ws;
    float* h            = (float*)w;          w += (size_t)NH * 4;       // 12.8 MB
    unsigned short* hbf = (unsigned short*)w; w += (size_t)NH * 2;       // 6.4
    char* txr           = w;                  w += (size_t)NH * 8;       // 25.6 (4 bufs)
    unsigned int* pairs4 = (unsigned int*)w;  w += (size_t)N_EDGES * 4;  // 6.4
    unsigned int* rc    = (unsigned int*)w;   w += (size_t)N_EDGES * 4;  // 6.4 (adjacent!)
    int* iperm          = (int*)w;            w += (size_t)N_EDGES * 4;  // 6.4
    int* row_ptr        = (int*)w;            w += 200192;
    int* cnt            = (int*)w;            w += 200192;
    float* dis          = (float*)w;          w += 200192;
    float* cWin = (float*)w; w += 2048;
    float* cbin = (float*)w; w += 256;
    float* ccW1 = (float*)w; w += 26112;
    float* ccb1 = (float*)w; w += 384;
    float* ccW2 = (float*)w; w += 2304;
    float* ccb2 = (float*)w; w += 128;
    float* clns = (float*)w; w += 768;
    float* clnb = (float*)w; w += 768;
    float* ceW1 = (float*)w; w += 32768;
    float* ceb1 = (float*)w; w += 256;
    float* ceW2 = (float*)w; w += 8192;
    float* ceb2 = (float*)w; w += 128;
    float* ceW3 = (float*)w; w += 128;
    float* ceb3 = (float*)w; w += 128;
    int* bsum = (int*)w; w += 1024;
    int* bpre = (int*)w; w += 1024;
    char* zero_base = w;
    float* stats = (float*)w; w += 1024;
    size_t zero_bytes = (size_t)(w - zero_base);
    float* coeffs = (float*)w; w += 128;
    int*   flag   = (int*)w;   w += 128;

    // setup-phase overlays (lifetimes disjoint with hosts):
    //  pcnt8  (12.8 MB) -> [pairs4|rc] contiguous region  [hist_row -> merge]
    //  pdeg   (12.8 MB) -> h region                        [hist_deg -> merge]
    //  pref16 (25.6 MB) -> txr                             [merge -> placeA]
    //  perm   (6.4 MB)  -> hbf region                      [placeA -> placeB]
    //  tmpP   (6.4 MB)  -> pairs4 region                   [edgepred -> k_out; pairs4 dead]
    unsigned int* pcnt_u32 = (unsigned int*)pairs4;
    unsigned char* pcnt8   = (unsigned char*)pairs4;
    float* pdeg            = (float*)h;
    unsigned short* pref16 = (unsigned short*)txr;
    int* perm              = (int*)hbf;
    float* tmpP            = (float*)pairs4;

    unsigned short* tx[4];
    for (int k = 0; k < 4; ++k) tx[k] = (unsigned short*)txr + (size_t)k * NH;
    unsigned short* ub = tx[0];   // k_uv runs after last spmm_ln: tx dead
    unsigned short* vb = tx[1];

    (void)hipMemsetAsync(zero_base, 0, zero_bytes, stream);

    k_detect<<<1, 64, 0, stream>>>(ew_r, flag);

    ConvArgs ca;
    const void* srcs[14] = {d_in[3], d_in[4], d_in[5], d_in[6], d_in[7], d_in[8], d_in[9],
                            d_in[10], d_in[11], d_in[12], d_in[13], d_in[14], d_in[15], d_in[16]};
    float* dsts[14] = {cWin, cbin, ccW1, ccb1, ccW2, ccb2, clns,
                       clnb, ceW1, ceb1, ceW2, ceb2, ceW3, ceb3};
    int sizes[14] = {512, 64, 6528, 96, 576, 18, 192, 192, 8192, 64, 2048, 32, 32, 1};
    int c = 0;
    for (int i = 0; i < 14; ++i) { ca.src[i] = srcs[i]; ca.dst[i] = dsts[i]; ca.cum[i] = c; c += sizes[i]; }
    ca.cum[14] = c;
    k_conv_small<<<(c + 255) / 256, 256, 0, stream>>>(ca, flag);

    k_hist_row<<<RSLC, 256, 0, stream>>>(ei, pcnt_u32);
    k_hist_deg<<<DSLC * NDSUB, 256, 0, stream>>>(ei, ew_r, flag, pdeg);
    k_merge<<<196, 256, 0, stream>>>(pcnt8, pdeg, cnt, dis, pref16, bsum);
    k_scan_top<<<1, 256, 0, stream>>>(bsum, bpre, row_ptr);
    k_scan_fin<<<196, 256, 0, stream>>>(cnt, bpre, row_ptr);
    k_placeA<<<RSLC, 256, 0, stream>>>(ei, row_ptr, pref16, perm, iperm);
    k_placeB<<<6250, 256, 0, stream>>>(ei, ew_r, dis, perm, flag, pairs4, rc);
    k_inproj<<<12500, 256, 0, stream>>>(x_r, cWin, cbin, h, hbf, flag);

    for (int l = 0; l < NLAYERS; ++l) {
        k_stats<<<400, 256, 0, stream>>>(h, stats + l * 80);
        k_coeffs<<<1, 64, 0, stream>>>(stats + l * 80, ccW1, ccb1, ccW2, ccb2, l,
                                       coeffs + l * 8);
        const unsigned short* src = hbf;
        for (int k = 0; k < 4; ++k) {
            k_spmm<<<12500, 256, 0, stream>>>(src, tx[k], row_ptr, pairs4);
            src = tx[k];
        }
        k_spmm_ln<<<12500, 256, 0, stream>>>(tx[3], row_ptr, pairs4, h, hbf,
                                             tx[0], tx[1], tx[2], tx[3],
                                             coeffs + l * 8, clns, clnb, l,
                                             (l == NLAYERS - 1) ? 1 : 0, d_out, flag);
    }

    k_uv<<<12500, 256, 0, stream>>>(h, ceW1, ub, vb);
    k_edgepred<<<1563, 256, 0, stream>>>(ub, vb, rc, ceb1, ceW2, ceb2, ceW3, ceb3, tmpP);
    k_out<<<6250, 256, 0, stream>>>(iperm, tmpP, d_out, flag);
}